// Round 1
// 361.835 us; speedup vs baseline: 1.0352x; 1.0352x over previous
//
#include <hip/hip_runtime.h>
#include <stdint.h>

typedef unsigned int u32;

// Journal:
//  R1: dual-path (f32 + bf16) with in-kernel dtype probe PASSED (absmax 0.0625).
//  R2: bf16-only FAILED with NaN -> proves d_in is float32.
//  R3: f32-only, 4 rays/thread float4 AoS. 374.6 us total; rocprof shows the
//      window = 2 x ~144 us poison fills (~940 MB each, 81-83% HBM peak,
//      harness-owned) + ~85 us kernel. Kernel effective BW 436 MB / 85 us
//      = 5.1 TB/s = 81% of the 6.29 TB/s copy ceiling.
//  R4 (this): the float4 AoS packing gives every load/store instruction a
//      48 B lane stride (lane l touches 48l+16k): 48 lines touched per wave
//      instruction to move 1 KB, 3x redundant L1 touches, and partial-line
//      stores needing L2 merge. Switch to ONE ray per thread with dwordx3
//      (12 B/lane, unit stride): every global access covers a minimal,
//      fully-contiguous 768 B/wave span. VMEM issue headroom is huge
//      (~7% utilized), so the extra instruction count is free.
//      Predict kernel ~85 -> ~70-75 us, total ~360-365 us.

struct __align__(4) F3 { float x, y, z; };

// Full per-ray physics in f32: translate->local, sphere intersect (C=(R,0,0)),
// aperture mask, normal oriented against V, Snell refraction w/ critical-angle
// clamp, renormalize. Identical math to R3 (which passed, absmax 0.0625).
__device__ __forceinline__ void trace_ray(
    float px, float py, float pz,
    float vx, float vy, float vz,
    float tox, float toy, float toz,
    float &gx, float &gy, float &gz,
    float &Tx, float &Ty, float &Tz,
    float &validf)
{
    const float R    = 50.0f;
    const float invR = 1.0f / 50.0f;
    const float eta  = 1.0f / 1.5f;

    float plx = px - tox, ply = py - toy, plz = pz - toz;   // SCALE = 1
    float ocx = plx - R, ocy = ply, ocz = plz;
    float b  = ocx*vx + ocy*vy + ocz*vz;
    float cc = ocx*ocx + ocy*ocy + ocz*ocz - R*R;
    float disc = b*b - cc;
    float sq = sqrtf(fmaxf(disc, 0.0f));
    float t  = -b - sq;                                     // near root
    float qx = plx + t*vx, qy = ply + t*vy, qz = plz + t*vz;
    float r2 = qy*qy + qz*qz;
    bool valid = (disc >= 0.0f) && (t > 0.0f) && (r2 <= 400.0f); // (DIAM/2)^2

    float nx = (qx - R) * invR, ny = qy * invR, nz = qz * invR;
    float vdn = vx*nx + vy*ny + vz*nz;
    if (vdn > 0.0f) { nx = -nx; ny = -ny; nz = -nz; }

    gx = valid ? qx + tox : px;
    gy = valid ? qy + toy : py;
    gz = valid ? qz + toz : pz;
    if (!valid) { nx = -1.0f; ny = 0.0f; nz = 0.0f; }

    float cosi = -(vx*nx + vy*ny + vz*nz);
    float k = fmaxf(1.0f - eta*eta*(1.0f - cosi*cosi), 0.0f);
    float fac = eta*cosi - sqrtf(k);
    float tx = eta*vx + fac*nx;
    float ty = eta*vy + fac*ny;
    float tz = eta*vz + fac*nz;
    float inv = rsqrtf(tx*tx + ty*ty + tz*tz);
    Tx = tx*inv; Ty = ty*inv; Tz = tz*inv;
    validf = valid ? 1.0f : 0.0f;
}

// One ray per thread. Every global access is unit-stride across the wave:
// loads/stores are dwordx3 at 12 B/lane (768 contiguous B per wave instr,
// minimal line touches), valid store is dword at 4 B/lane.
__global__ __launch_bounds__(256) void optics_f32_v2(
    const float* __restrict__ P, const float* __restrict__ V,
    const float* __restrict__ TO, float* __restrict__ O, int nrays)
{
    int i = blockIdx.x * blockDim.x + threadIdx.x;
    if (i >= nrays) return;

    const float tox = TO[0], toy = TO[1], toz = TO[2];

    const F3* __restrict__ P3 = (const F3*)P;
    const F3* __restrict__ V3 = (const F3*)V;
    F3 p = P3[i];
    F3 v = V3[i];

    float gx, gy, gz, Tx, Ty, Tz, vl;
    trace_ray(p.x, p.y, p.z, v.x, v.y, v.z, tox, toy, toz,
              gx, gy, gz, Tx, Ty, Tz, vl);

    F3* __restrict__ G3 = (F3*)O;                                   // pt  [0, 3N)
    F3* __restrict__ T3 = (F3*)(O + 3 * (size_t)nrays);             // T   [3N, 6N)
    float* __restrict__ VL = O + 6 * (size_t)nrays;                 // valid [6N, 7N)

    F3 g; g.x = gx; g.y = gy; g.z = gz;
    F3 tt; tt.x = Tx; tt.y = Ty; tt.z = Tz;
    G3[i] = g;
    T3[i] = tt;
    VL[i] = vl;
}

extern "C" void kernel_launch(void* const* d_in, const int* in_sizes, int n_in,
                              void* d_out, int out_size, void* d_ws, size_t ws_size,
                              hipStream_t stream) {
    int nrays = in_sizes[0] / 3;               // 8,388,608
    int blocks = (nrays + 255) / 256;          // 32768 blocks, 1 ray/thread
    optics_f32_v2<<<blocks, 256, 0, stream>>>(
        (const float*)d_in[0], (const float*)d_in[1], (const float*)d_in[2],
        (float*)d_out, nrays);
}